// Round 3
// baseline (3234.412 us; speedup 1.0000x reference)
//
#include <hip/hip_runtime.h>
#include <cstddef>
#include <cstdint>

// CellNetwork on MI355X — fp32, round 3 (no bench yet: broker at capacity 3x).
// Structure:
//  * spmm(idx,val, he@W) == spmm(idx,val,he) @ W  -> sparse gather + dense GEMM.
//  * all segment_sums converted to CSR-gather (built on-device each call; no fp atomics).
//  * CWNN layer fully fused: gemm3_gather computes
//      OUT = relu( A@W0 + (Ldo@A)@W1 + (Lup@A)@W2 )
//    in ONE kernel; the Ldo/Lup gathers happen inside the A-tile LDS staging
//    (CSR-weighted row sums), eliminating the G intermediate write+read
//    (~1.2 GB HBM/L3 traffic) and 6 dispatches vs round 2.
//  * workspace: ~238 MB (2 E-buffers + 2 N-buffers + CSR arrays).

static inline int cdiv_h(int a, int b){ return (a + b - 1) / b; }

// ---------------- CSR build ----------------

__global__ void hist_key(const int* __restrict__ keys, int* __restrict__ counts, int n){
  int i = blockIdx.x * blockDim.x + threadIdx.x;
  if (i < n) atomicAdd(&counts[keys[i]], 1);
}

__global__ void hist_two(const int* __restrict__ a, const int* __restrict__ b,
                         int* __restrict__ counts, int n){
  int i = blockIdx.x * blockDim.x + threadIdx.x;
  if (i < n){ atomicAdd(&counts[a[i]], 1); atomicAdd(&counts[b[i]], 1); }
}

#define SCAN_CHUNK 2048

__global__ void scan_local(const int* __restrict__ cnt, int* __restrict__ offs,
                           int* __restrict__ partials, int n){
  __shared__ int sd[256];
  int t = threadIdx.x;
  int base = blockIdx.x * SCAN_CHUNK + t * 8;
  int v[8]; int sum = 0;
  #pragma unroll
  for (int i = 0; i < 8; i++){ int idx = base + i; v[i] = (idx < n) ? cnt[idx] : 0; sum += v[i]; }
  sd[t] = sum; __syncthreads();
  for (int off = 1; off < 256; off <<= 1){
    int x = (t >= off) ? sd[t - off] : 0;
    __syncthreads();
    sd[t] += x;
    __syncthreads();
  }
  if (t == 255) partials[blockIdx.x] = sd[255];
  int run = sd[t] - sum;   // exclusive prefix of this thread's chunk within block
  #pragma unroll
  for (int i = 0; i < 8; i++){ int idx = base + i; if (idx < n) offs[idx] = run; run += v[i]; }
}

__global__ void scan_partials_k(int* partials, int nb){
  __shared__ int sd[256];
  int t = threadIdx.x;
  int orig = (t < nb) ? partials[t] : 0;
  sd[t] = orig; __syncthreads();
  for (int off = 1; off < 256; off <<= 1){
    int x = (t >= off) ? sd[t - off] : 0;
    __syncthreads();
    sd[t] += x;
    __syncthreads();
  }
  if (t < nb) partials[t] = sd[t] - orig;  // exclusive
}

__global__ void scan_add(int* __restrict__ offs, const int* __restrict__ partials,
                         int n, int total){
  int i = blockIdx.x * blockDim.x + threadIdx.x;
  if (i < n) offs[i] += partials[i / SCAN_CHUNK];
  if (i == 0) offs[n] = total;
}

__global__ void fill_plain(const int* __restrict__ keys, const int* __restrict__ vals,
                           int* __restrict__ cursor, int* __restrict__ ent, int n){
  int i = blockIdx.x * blockDim.x + threadIdx.x;
  if (i < n){ int p = atomicAdd(&cursor[keys[i]], 1); ent[p] = vals[i]; }
}

__global__ void fill_wval(const int* __restrict__ rows, const int* __restrict__ cols,
                          const float* __restrict__ v, int* __restrict__ cursor,
                          int* __restrict__ entc, float* __restrict__ entv, int n){
  int i = blockIdx.x * blockDim.x + threadIdx.x;
  if (i < n){
    int p = atomicAdd(&cursor[rows[i]], 1);
    entc[p] = cols[i]; entv[p] = v[i];
  }
}

__global__ void fill_two(const int* __restrict__ a, const int* __restrict__ b,
                         int* __restrict__ cursor, int* __restrict__ ent, int n){
  int i = blockIdx.x * blockDim.x + threadIdx.x;
  if (i < n){
    int p = atomicAdd(&cursor[a[i]], 1); ent[p] = i;
    int q = atomicAdd(&cursor[b[i]], 1); ent[q] = i;
  }
}

// ---------------- CSR gather (segment-sum as gather; no atomics) ----------------
// out[r, 0:128] = (selfsrc ? selfsrc[r] : 0) + sum_j src[ent[j]]
// 32 lanes per row, float4 per lane. ldout in floats.

__global__ void gather_rows(const float* __restrict__ src, float* __restrict__ out,
                            const int* __restrict__ offs, const int* __restrict__ ent,
                            const float* __restrict__ selfsrc,
                            int nrows, int ldout){
  int r = blockIdx.x * 8 + (threadIdx.x >> 5);
  if (r >= nrows) return;
  int d4 = (threadIdx.x & 31) * 4;
  float4 acc;
  if (selfsrc) acc = *(const float4*)&selfsrc[(size_t)r * 128 + d4];
  else         acc = make_float4(0.f, 0.f, 0.f, 0.f);
  int b = offs[r], e = offs[r + 1];
  for (int j = b; j < e; j++){
    int c = ent[j];
    float4 s = *(const float4*)&src[(size_t)c * 128 + d4];
    acc.x += s.x; acc.y += s.y; acc.z += s.z; acc.w += s.w;
  }
  *(float4*)&out[(size_t)r * ldout + d4] = acc;
}

// ---------------- fp32 GEMM: out[M x 128] = relu?(in[M x 128] @ W[128 x 128]) ------
// 256 threads, 128-row tile, per-thread 8x8, K chunked by 32 through LDS.

__global__ __launch_bounds__(256) void gemm128(
    const float* __restrict__ in, const float* __restrict__ W,
    float* __restrict__ out, int M, int ldout, int relu){
  __shared__ float sA[32][132];   // [k][row], padded to spread banks
  __shared__ float sW[32][128];   // [k][col]
  int t  = threadIdx.x;
  int m0 = blockIdx.x * 128;
  int rg = t >> 4;       // 16 row-groups * 8 rows
  int cg = t & 15;       // 16 col-groups * 8 cols
  float acc[8][8];
  #pragma unroll
  for (int i = 0; i < 8; i++)
    #pragma unroll
    for (int j = 0; j < 8; j++) acc[i][j] = 0.f;

  for (int kc = 0; kc < 128; kc += 32){
    #pragma unroll
    for (int ii = 0; ii < 4; ii++){
      int s  = t + ii * 256;           // 1024 float4 slots: 128 rows x 8 k4
      int r  = s >> 3;
      int k4 = (s & 7) << 2;
      int gr = m0 + r;
      float4 v = (gr < M) ? *(const float4*)&in[(size_t)gr * 128 + kc + k4]
                          : make_float4(0.f, 0.f, 0.f, 0.f);
      sA[k4 + 0][r] = v.x; sA[k4 + 1][r] = v.y; sA[k4 + 2][r] = v.z; sA[k4 + 3][r] = v.w;
    }
    #pragma unroll
    for (int ii = 0; ii < 4; ii++){
      int s  = t + ii * 256;
      int kr = s >> 5;
      int c4 = (s & 31) << 2;
      *(float4*)&sW[kr][c4] = *(const float4*)&W[(size_t)(kc + kr) * 128 + c4];
    }
    __syncthreads();
    #pragma unroll
    for (int k = 0; k < 32; k++){
      float4 a0 = *(const float4*)&sA[k][rg * 8];
      float4 a1 = *(const float4*)&sA[k][rg * 8 + 4];
      float4 w0 = *(const float4*)&sW[k][cg * 8];
      float4 w1 = *(const float4*)&sW[k][cg * 8 + 4];
      float a[8] = {a0.x, a0.y, a0.z, a0.w, a1.x, a1.y, a1.z, a1.w};
      float w[8] = {w0.x, w0.y, w0.z, w0.w, w1.x, w1.y, w1.z, w1.w};
      #pragma unroll
      for (int i = 0; i < 8; i++)
        #pragma unroll
        for (int j = 0; j < 8; j++)
          acc[i][j] = fmaf(a[i], w[j], acc[i][j]);
    }
    __syncthreads();
  }
  #pragma unroll
  for (int i = 0; i < 8; i++){
    int gr = m0 + rg * 8 + i;
    if (gr >= M) continue;
    float* op = out + (size_t)gr * ldout + cg * 8;
    #pragma unroll
    for (int jj = 0; jj < 8; jj += 4){
      float4 o = make_float4(acc[i][jj], acc[i][jj + 1], acc[i][jj + 2], acc[i][jj + 3]);
      if (relu){
        o.x = fmaxf(o.x, 0.f); o.y = fmaxf(o.y, 0.f);
        o.z = fmaxf(o.z, 0.f); o.w = fmaxf(o.w, 0.f);
      }
      *(float4*)&op[jj] = o;
    }
  }
}

// ------- fused CWNN layer: OUT = relu?( A@Wa + (Ldo@A)@Wb + (Lup@A)@Wc ) ----------
// Same tiling as gemm128; three source passes share one accumulator. Passes 1/2
// build the A-tile in LDS via CSR-weighted gather of A rows (avg 2 entries/row),
// so the sparse products never touch HBM as intermediates.

__global__ __launch_bounds__(256) void gemm3_gather(
    const float* __restrict__ A,
    const float* __restrict__ Wa, const float* __restrict__ Wb, const float* __restrict__ Wc,
    const int* __restrict__ offs_d, const int* __restrict__ entc_d, const float* __restrict__ entv_d,
    const int* __restrict__ offs_u, const int* __restrict__ entc_u, const float* __restrict__ entv_u,
    float* __restrict__ out, int M, int relu){
  __shared__ float sA[32][132];
  __shared__ float sW[32][128];
  int t  = threadIdx.x;
  int m0 = blockIdx.x * 128;
  int rg = t >> 4;
  int cg = t & 15;
  float acc[8][8];
  #pragma unroll
  for (int i = 0; i < 8; i++)
    #pragma unroll
    for (int j = 0; j < 8; j++) acc[i][j] = 0.f;

  #pragma unroll 1
  for (int pass = 0; pass < 3; pass++){
    const float* W = (pass == 0) ? Wa : (pass == 1) ? Wb : Wc;
    const int*   offs = (pass == 1) ? offs_d : offs_u;
    const int*   entc = (pass == 1) ? entc_d : entc_u;
    const float* entv = (pass == 1) ? entv_d : entv_u;

    #pragma unroll 1
    for (int kc = 0; kc < 128; kc += 32){
      // ---- stage A-tile (transposed) ----
      #pragma unroll
      for (int ii = 0; ii < 4; ii++){
        int sl = t + ii * 256;          // 1024 slots: 128 rows x 8 k4-groups
        int r  = sl >> 3;
        int k4 = (sl & 7) << 2;
        int gr = m0 + r;
        float4 v = make_float4(0.f, 0.f, 0.f, 0.f);
        if (gr < M){
          if (pass == 0){
            v = *(const float4*)&A[(size_t)gr * 128 + kc + k4];
          } else {
            int b = offs[gr], e = offs[gr + 1];
            for (int j = b; j < e; j++){
              int c = entc[j];
              float w = entv[j];
              float4 s4 = *(const float4*)&A[(size_t)c * 128 + kc + k4];
              v.x += w * s4.x; v.y += w * s4.y; v.z += w * s4.z; v.w += w * s4.w;
            }
          }
        }
        sA[k4 + 0][r] = v.x; sA[k4 + 1][r] = v.y; sA[k4 + 2][r] = v.z; sA[k4 + 3][r] = v.w;
      }
      // ---- stage W chunk ----
      #pragma unroll
      for (int ii = 0; ii < 4; ii++){
        int sl = t + ii * 256;
        int kr = sl >> 5;
        int c4 = (sl & 31) << 2;
        *(float4*)&sW[kr][c4] = *(const float4*)&W[(size_t)(kc + kr) * 128 + c4];
      }
      __syncthreads();
      // ---- accumulate ----
      #pragma unroll
      for (int k = 0; k < 32; k++){
        float4 a0 = *(const float4*)&sA[k][rg * 8];
        float4 a1 = *(const float4*)&sA[k][rg * 8 + 4];
        float4 w0 = *(const float4*)&sW[k][cg * 8];
        float4 w1 = *(const float4*)&sW[k][cg * 8 + 4];
        float a[8] = {a0.x, a0.y, a0.z, a0.w, a1.x, a1.y, a1.z, a1.w};
        float w[8] = {w0.x, w0.y, w0.z, w0.w, w1.x, w1.y, w1.z, w1.w};
        #pragma unroll
        for (int i = 0; i < 8; i++)
          #pragma unroll
          for (int j = 0; j < 8; j++)
            acc[i][j] = fmaf(a[i], w[j], acc[i][j]);
      }
      __syncthreads();
    }
  }
  // ---- epilogue ----
  #pragma unroll
  for (int i = 0; i < 8; i++){
    int gr = m0 + rg * 8 + i;
    if (gr >= M) continue;
    float* op = out + (size_t)gr * 128 + cg * 8;
    #pragma unroll
    for (int jj = 0; jj < 8; jj += 4){
      float4 o = make_float4(acc[i][jj], acc[i][jj + 1], acc[i][jj + 2], acc[i][jj + 3]);
      if (relu){
        o.x = fmaxf(o.x, 0.f); o.y = fmaxf(o.y, 0.f);
        o.z = fmaxf(o.z, 0.f); o.w = fmaxf(o.w, 0.f);
      }
      *(float4*)&op[jj] = o;
    }
  }
}

// ---------------- launch ----------------

extern "C" void kernel_launch(void* const* d_in, const int* in_sizes, int n_in,
                              void* d_out, int out_size, void* d_ws, size_t ws_size,
                              hipStream_t stream){
  const float* x    = (const float*)d_in[0];
  const float* xe   = (const float*)d_in[1];
  const float* gW   = (const float*)d_in[2];
  const float* W0   = (const float*)d_in[3];
  const float* W1   = (const float*)d_in[4];
  const float* W2   = (const float*)d_in[5];
  const float* ldoV = (const float*)d_in[6];
  const float* lupV = (const float*)d_in[7];
  const int*   edges= (const int*)d_in[8];
  const int*   rowi = (const int*)d_in[9];
  const int*   coli = (const int*)d_in[10];
  const int*   ldoI = (const int*)d_in[11];
  const int*   lupI = (const int*)d_in[12];
  (void)n_in; (void)out_size;

  const int D   = 128;
  const int N   = in_sizes[0] / D;
  const int E   = in_sizes[1] / D;
  const int NNZ = in_sizes[6];
  const int L   = in_sizes[2] / (D * D);

  const int* srcN = edges;        // edges[0] = src
  const int* dstN = edges + E;    // edges[1] = dst
  const int* ldoR = ldoI;         const int* ldoC = ldoI + NNZ;
  const int* lupR = lupI;         const int* lupC = lupI + NNZ;

  // ---- carve workspace (~238 MB total) ----
  size_t off = 0;
  auto carve = [&](size_t bytes) -> void* {
    void* p = (char*)d_ws + off;
    off += (bytes + 255) & ~(size_t)255;
    return p;
  };
  float* EA  = (float*)carve((size_t)E * D * 4);   // ping
  float* EC  = (float*)carve((size_t)E * D * 4);   // pong
  float* hA  = (float*)carve((size_t)N * D * 4);
  float* hB  = (float*)carve((size_t)N * D * 4);
  int* offs_g = (int*)carve((size_t)(N + 1) * 4);
  int* cnt_g  = (int*)carve((size_t)N * 4);
  int* ent_g  = (int*)carve((size_t)E * 4);
  int* offs_d = (int*)carve((size_t)(E + 1) * 4);
  int* cnt_d  = (int*)carve((size_t)E * 4);
  int* entc_d = (int*)carve((size_t)NNZ * 4);
  float* entv_d = (float*)carve((size_t)NNZ * 4);
  int* offs_u = (int*)carve((size_t)(E + 1) * 4);
  int* cnt_u  = (int*)carve((size_t)E * 4);
  int* entc_u = (int*)carve((size_t)NNZ * 4);
  float* entv_u = (float*)carve((size_t)NNZ * 4);
  int* offs_f = (int*)carve((size_t)(N + 1) * 4);
  int* cnt_f  = (int*)carve((size_t)N * 4);
  int* ent_f  = (int*)carve((size_t)2 * E * 4);
  int* partials = (int*)carve(256 * 4);
  if (off > ws_size) return;  // workspace too small: fail loudly via poisoned output

  auto scan3 = [&](int* cnt, int* offs, int n, int total){
    int nb = (n + SCAN_CHUNK - 1) / SCAN_CHUNK;   // <= 196 for n=400000
    scan_local<<<nb, 256, 0, stream>>>(cnt, offs, partials, n);
    scan_partials_k<<<1, 256, 0, stream>>>(partials, nb);
    scan_add<<<cdiv_h(n, 256), 256, 0, stream>>>(offs, partials, n, total);
  };

  // ---- CSR: GNN (group srcs by dst) ----
  hipMemsetAsync(cnt_g, 0, (size_t)N * 4, stream);
  hist_key<<<cdiv_h(E, 256), 256, 0, stream>>>(dstN, cnt_g, E);
  scan3(cnt_g, offs_g, N, E);
  hipMemcpyAsync(cnt_g, offs_g, (size_t)N * 4, hipMemcpyDeviceToDevice, stream);
  fill_plain<<<cdiv_h(E, 256), 256, 0, stream>>>(dstN, srcN, cnt_g, ent_g, E);

  // ---- CSR: Ldo ----
  hipMemsetAsync(cnt_d, 0, (size_t)E * 4, stream);
  hist_key<<<cdiv_h(NNZ, 256), 256, 0, stream>>>(ldoR, cnt_d, NNZ);
  scan3(cnt_d, offs_d, E, NNZ);
  hipMemcpyAsync(cnt_d, offs_d, (size_t)E * 4, hipMemcpyDeviceToDevice, stream);
  fill_wval<<<cdiv_h(NNZ, 256), 256, 0, stream>>>(ldoR, ldoC, ldoV, cnt_d, entc_d, entv_d, NNZ);

  // ---- CSR: Lup ----
  hipMemsetAsync(cnt_u, 0, (size_t)E * 4, stream);
  hist_key<<<cdiv_h(NNZ, 256), 256, 0, stream>>>(lupR, cnt_u, NNZ);
  scan3(cnt_u, offs_u, E, NNZ);
  hipMemcpyAsync(cnt_u, offs_u, (size_t)E * 4, hipMemcpyDeviceToDevice, stream);
  fill_wval<<<cdiv_h(NNZ, 256), 256, 0, stream>>>(lupR, lupC, lupV, cnt_u, entc_u, entv_u, NNZ);

  // ---- CSR: final dual scatter (row + col combined) ----
  hipMemsetAsync(cnt_f, 0, (size_t)N * 4, stream);
  hist_two<<<cdiv_h(E, 256), 256, 0, stream>>>(rowi, coli, cnt_f, E);
  scan3(cnt_f, offs_f, N, 2 * E);
  hipMemcpyAsync(cnt_f, offs_f, (size_t)N * 4, hipMemcpyDeviceToDevice, stream);
  fill_two<<<cdiv_h(E, 256), 256, 0, stream>>>(rowi, coli, cnt_f, ent_f, E);

  // ---- GNN over nodes: h = relu((h + agg) @ W) x3; last layer -> d_out[:, :128] ----
  const float* hcur = x;
  for (int i = 0; i < L; i++){
    gather_rows<<<cdiv_h(N, 8), 256, 0, stream>>>(hcur, hA, offs_g, ent_g, hcur, N, 128);
    float* hdst = (i == L - 1) ? (float*)d_out : hB;
    int ldo = (i == L - 1) ? 256 : 128;
    gemm128<<<cdiv_h(N, 128), 256, 0, stream>>>(hA, gW + (size_t)i * D * D, hdst, N, ldo, 1);
    hcur = hB;
  }

  // ---- CWNN over cells: one fused kernel per layer ----
  const float* A = xe;
  float* outsel[3] = {EA, EC, EA};
  for (int i = 0; i < L; i++){
    float* OUT = outsel[i];
    gemm3_gather<<<cdiv_h(E, 128), 256, 0, stream>>>(
        A,
        W0 + (size_t)i * D * D, W1 + (size_t)i * D * D, W2 + (size_t)i * D * D,
        offs_d, entc_d, entv_d, offs_u, entc_u, entv_u,
        OUT, E, 1);
    A = OUT;
  }

  // ---- xed = seg_sum(he, row) + seg_sum(he, col) -> d_out[:, 128:256] ----
  gather_rows<<<cdiv_h(N, 8), 256, 0, stream>>>(A, (float*)d_out + 128, offs_f, ent_f,
                                                nullptr, N, 256);
}

// Round 6
// 943.511 us; speedup vs baseline: 3.4281x; 3.4281x over previous
//
#include <hip/hip_runtime.h>
#include <cstddef>
#include <cstdint>

// CellNetwork on MI355X — round 6: CWNN path in bf16 via MFMA.
//  * R3 measured: fused gather-in-GEMM latency-bound (VALU 16.6%, occ 10.6%) -> unfused.
//  * CWNN (94% of GEMM FLOPs): activations+weights bf16, fp32 accum, mfma_f32_16x16x32_bf16.
//    k-permutation invariance: A/B frags share one (lane,elem)->k map, so only the
//    HW-verified C/D map (col=lane&15, row=(lane>>4)*4+reg) must be right.
//  * GNN (large-magnitude h, 6% of FLOPs) stays fp32 vector for accuracy.
//  * Workspace byte-identical to R3-proven 237,602,048 B (W-bf16 aliases hA post-GNN).

using bf16x8 = __attribute__((ext_vector_type(8))) short;
using f32x4  = __attribute__((ext_vector_type(4))) float;
typedef unsigned short u16;
typedef unsigned int   u32;

static inline int cdiv_h(int a, int b){ return (a + b - 1) / b; }

__device__ inline float bflo(u32 u){ return __uint_as_float(u << 16); }
__device__ inline float bfhi(u32 u){ return __uint_as_float(u & 0xFFFF0000u); }
__device__ inline u32 f2bf(float f){            // RNE fp32->bf16 (no NaN concern here)
  u32 u = __float_as_uint(f);
  return (u + 0x7FFFu + ((u >> 16) & 1u)) >> 16;
}
__device__ inline u32 pack2(float a, float b){ return f2bf(a) | (f2bf(b) << 16); }

// ---------------- CSR build ----------------

__global__ void hist_key(const int* __restrict__ keys, int* __restrict__ counts, int n){
  int i = blockIdx.x * blockDim.x + threadIdx.x;
  if (i < n) atomicAdd(&counts[keys[i]], 1);
}

__global__ void hist_two(const int* __restrict__ a, const int* __restrict__ b,
                         int* __restrict__ counts, int n){
  int i = blockIdx.x * blockDim.x + threadIdx.x;
  if (i < n){ atomicAdd(&counts[a[i]], 1); atomicAdd(&counts[b[i]], 1); }
}

#define SCAN_CHUNK 2048

__global__ void scan_local(const int* __restrict__ cnt, int* __restrict__ offs,
                           int* __restrict__ partials, int n){
  __shared__ int sd[256];
  int t = threadIdx.x;
  int base = blockIdx.x * SCAN_CHUNK + t * 8;
  int v[8]; int sum = 0;
  #pragma unroll
  for (int i = 0; i < 8; i++){ int idx = base + i; v[i] = (idx < n) ? cnt[idx] : 0; sum += v[i]; }
  sd[t] = sum; __syncthreads();
  for (int off = 1; off < 256; off <<= 1){
    int x = (t >= off) ? sd[t - off] : 0;
    __syncthreads();
    sd[t] += x;
    __syncthreads();
  }
  if (t == 255) partials[blockIdx.x] = sd[255];
  int run = sd[t] - sum;
  #pragma unroll
  for (int i = 0; i < 8; i++){ int idx = base + i; if (idx < n) offs[idx] = run; run += v[i]; }
}

__global__ void scan_partials_k(int* partials, int nb){
  __shared__ int sd[256];
  int t = threadIdx.x;
  int orig = (t < nb) ? partials[t] : 0;
  sd[t] = orig; __syncthreads();
  for (int off = 1; off < 256; off <<= 1){
    int x = (t >= off) ? sd[t - off] : 0;
    __syncthreads();
    sd[t] += x;
    __syncthreads();
  }
  if (t < nb) partials[t] = sd[t] - orig;
}

__global__ void scan_add(int* __restrict__ offs, const int* __restrict__ partials,
                         int n, int total){
  int i = blockIdx.x * blockDim.x + threadIdx.x;
  if (i < n) offs[i] += partials[i / SCAN_CHUNK];
  if (i == 0) offs[n] = total;
}

__global__ void fill_plain(const int* __restrict__ keys, const int* __restrict__ vals,
                           int* __restrict__ cursor, int* __restrict__ ent, int n){
  int i = blockIdx.x * blockDim.x + threadIdx.x;
  if (i < n){ int p = atomicAdd(&cursor[keys[i]], 1); ent[p] = vals[i]; }
}

__global__ void fill_wval(const int* __restrict__ rows, const int* __restrict__ cols,
                          const float* __restrict__ v, int* __restrict__ cursor,
                          int* __restrict__ entc, float* __restrict__ entv, int n){
  int i = blockIdx.x * blockDim.x + threadIdx.x;
  if (i < n){
    int p = atomicAdd(&cursor[rows[i]], 1);
    entc[p] = cols[i]; entv[p] = v[i];
  }
}

__global__ void fill_two(const int* __restrict__ a, const int* __restrict__ b,
                         int* __restrict__ cursor, int* __restrict__ ent, int n){
  int i = blockIdx.x * blockDim.x + threadIdx.x;
  if (i < n){
    int p = atomicAdd(&cursor[a[i]], 1); ent[p] = i;
    int q = atomicAdd(&cursor[b[i]], 1); ent[q] = i;
  }
}

// ---------------- fp32 CSR gather (GNN; self + unweighted sum) ----------------

__global__ void gather_f32(const float* __restrict__ src, float* __restrict__ out,
                           const int* __restrict__ offs, const int* __restrict__ ent,
                           const float* __restrict__ selfsrc, int nrows){
  int r = blockIdx.x * 8 + (threadIdx.x >> 5);
  if (r >= nrows) return;
  int d4 = (threadIdx.x & 31) * 4;
  float4 acc0, acc1 = make_float4(0.f, 0.f, 0.f, 0.f);
  acc0 = *(const float4*)&selfsrc[(size_t)r * 128 + d4];
  int b = offs[r], e = offs[r + 1];
  int j = b;
  for (; j + 1 < e; j += 2){
    int c0 = ent[j], c1 = ent[j + 1];
    float4 s0 = *(const float4*)&src[(size_t)c0 * 128 + d4];
    float4 s1 = *(const float4*)&src[(size_t)c1 * 128 + d4];
    acc0.x += s0.x; acc0.y += s0.y; acc0.z += s0.z; acc0.w += s0.w;
    acc1.x += s1.x; acc1.y += s1.y; acc1.z += s1.z; acc1.w += s1.w;
  }
  if (j < e){
    int c = ent[j];
    float4 s = *(const float4*)&src[(size_t)c * 128 + d4];
    acc0.x += s.x; acc0.y += s.y; acc0.z += s.z; acc0.w += s.w;
  }
  acc0.x += acc1.x; acc0.y += acc1.y; acc0.z += acc1.z; acc0.w += acc1.w;
  *(float4*)&out[(size_t)r * 128 + d4] = acc0;
}

// ---------------- bf16 CSR gathers (CWNN + final) ----------------

__global__ void gather_bf16(const u16* __restrict__ src, u16* __restrict__ out,
                            const int* __restrict__ offs, const int* __restrict__ ent,
                            const float* __restrict__ evals, int nrows){
  int r = blockIdx.x * 8 + (threadIdx.x >> 5);
  if (r >= nrows) return;
  int d4 = (threadIdx.x & 31) * 4;
  float a0=0.f,a1=0.f,a2=0.f,a3=0.f, b0=0.f,b1=0.f,b2=0.f,b3=0.f;
  int b = offs[r], e = offs[r + 1];
  int j = b;
  for (; j + 1 < e; j += 2){
    int c0 = ent[j], c1 = ent[j + 1];
    float w0 = evals[j], w1 = evals[j + 1];
    uint2 s0 = *(const uint2*)&src[(size_t)c0 * 128 + d4];
    uint2 s1 = *(const uint2*)&src[(size_t)c1 * 128 + d4];
    a0 += w0 * bflo(s0.x); a1 += w0 * bfhi(s0.x); a2 += w0 * bflo(s0.y); a3 += w0 * bfhi(s0.y);
    b0 += w1 * bflo(s1.x); b1 += w1 * bfhi(s1.x); b2 += w1 * bflo(s1.y); b3 += w1 * bfhi(s1.y);
  }
  if (j < e){
    int c = ent[j];
    float w = evals[j];
    uint2 s = *(const uint2*)&src[(size_t)c * 128 + d4];
    a0 += w * bflo(s.x); a1 += w * bfhi(s.x); a2 += w * bflo(s.y); a3 += w * bfhi(s.y);
  }
  a0 += b0; a1 += b1; a2 += b2; a3 += b3;
  uint2 o; o.x = pack2(a0, a1); o.y = pack2(a2, a3);
  *(uint2*)&out[(size_t)r * 128 + d4] = o;
}

__global__ void gather_final(const u16* __restrict__ src, float* __restrict__ out,
                             const int* __restrict__ offs, const int* __restrict__ ent,
                             int nrows, int ldout){
  int r = blockIdx.x * 8 + (threadIdx.x >> 5);
  if (r >= nrows) return;
  int d4 = (threadIdx.x & 31) * 4;
  float a0=0.f,a1=0.f,a2=0.f,a3=0.f, b0=0.f,b1=0.f,b2=0.f,b3=0.f;
  int b = offs[r], e = offs[r + 1];
  int j = b;
  for (; j + 1 < e; j += 2){
    int c0 = ent[j], c1 = ent[j + 1];
    uint2 s0 = *(const uint2*)&src[(size_t)c0 * 128 + d4];
    uint2 s1 = *(const uint2*)&src[(size_t)c1 * 128 + d4];
    a0 += bflo(s0.x); a1 += bfhi(s0.x); a2 += bflo(s0.y); a3 += bfhi(s0.y);
    b0 += bflo(s1.x); b1 += bfhi(s1.x); b2 += bflo(s1.y); b3 += bfhi(s1.y);
  }
  if (j < e){
    int c = ent[j];
    uint2 s = *(const uint2*)&src[(size_t)c * 128 + d4];
    a0 += bflo(s.x); a1 += bfhi(s.x); a2 += bflo(s.y); a3 += bfhi(s.y);
  }
  float4 o = make_float4(a0 + b0, a1 + b1, a2 + b2, a3 + b3);
  *(float4*)&out[(size_t)r * ldout + d4] = o;
}

// ---------------- fp32 -> bf16 conversion (8 elems/thread) ----------------

__global__ void cvt_f32_bf16(const float* __restrict__ src, u16* __restrict__ dst, int n8){
  int i = blockIdx.x * blockDim.x + threadIdx.x;
  if (i >= n8) return;
  const float4* s = (const float4*)(src + (size_t)i * 8);
  float4 a = s[0], c = s[1];
  *(uint4*)(dst + (size_t)i * 8) =
      make_uint4(pack2(a.x, a.y), pack2(a.z, a.w), pack2(c.x, c.y), pack2(c.z, c.w));
}

// ---------------- fp32 GEMM (GNN): out = relu(in @ W), ldout param ----------------

__global__ __launch_bounds__(256) void gemm_f32(
    const float* __restrict__ in, const float* __restrict__ W,
    float* __restrict__ out, int M, int ldout){
  __shared__ float sA[32][132];
  __shared__ float sW[32][128];
  int t  = threadIdx.x;
  int m0 = blockIdx.x * 128;
  int rg = t >> 4;
  int cg = t & 15;
  float acc[8][8];
  #pragma unroll
  for (int i = 0; i < 8; i++)
    #pragma unroll
    for (int j = 0; j < 8; j++) acc[i][j] = 0.f;

  for (int kc = 0; kc < 128; kc += 32){
    #pragma unroll
    for (int ii = 0; ii < 4; ii++){
      int s  = t + ii * 256;
      int r  = s >> 3;
      int k4 = (s & 7) << 2;
      int gr = m0 + r;
      float4 v = (gr < M) ? *(const float4*)&in[(size_t)gr * 128 + kc + k4]
                          : make_float4(0.f, 0.f, 0.f, 0.f);
      sA[k4 + 0][r] = v.x; sA[k4 + 1][r] = v.y; sA[k4 + 2][r] = v.z; sA[k4 + 3][r] = v.w;
    }
    #pragma unroll
    for (int ii = 0; ii < 4; ii++){
      int s  = t + ii * 256;
      int kr = s >> 5;
      int c4 = (s & 31) << 2;
      *(float4*)&sW[kr][c4] = *(const float4*)&W[(size_t)(kc + kr) * 128 + c4];
    }
    __syncthreads();
    #pragma unroll
    for (int k = 0; k < 32; k++){
      float4 a0 = *(const float4*)&sA[k][rg * 8];
      float4 a1 = *(const float4*)&sA[k][rg * 8 + 4];
      float4 w0 = *(const float4*)&sW[k][cg * 8];
      float4 w1 = *(const float4*)&sW[k][cg * 8 + 4];
      float a[8] = {a0.x, a0.y, a0.z, a0.w, a1.x, a1.y, a1.z, a1.w};
      float w[8] = {w0.x, w0.y, w0.z, w0.w, w1.x, w1.y, w1.z, w1.w};
      #pragma unroll
      for (int i = 0; i < 8; i++)
        #pragma unroll
        for (int j = 0; j < 8; j++)
          acc[i][j] = fmaf(a[i], w[j], acc[i][j]);
    }
    __syncthreads();
  }
  #pragma unroll
  for (int i = 0; i < 8; i++){
    int gr = m0 + rg * 8 + i;
    if (gr >= M) continue;
    float* op = out + (size_t)gr * ldout + cg * 8;
    #pragma unroll
    for (int jj = 0; jj < 8; jj += 4){
      float4 o = make_float4(fmaxf(acc[i][jj], 0.f), fmaxf(acc[i][jj + 1], 0.f),
                             fmaxf(acc[i][jj + 2], 0.f), fmaxf(acc[i][jj + 3], 0.f));
      *(float4*)&op[jj] = o;
    }
  }
}

// ---------------- bf16 MFMA GEMM (CWNN): out = relu(sum_s As@Ws), bf16 out ----------
// BM=BN=128, 4 waves x (32 rows x 128 cols), K=128 per source in chunks of 32.
// sA[128][40], sW[128][40] bf16 (40-elem rows: 80 B -> 16B-aligned, ~2-way banks).
// sW stores W transposed (sW[n][k]) so B-frags are contiguous 8x bf16.

template<int NS>
__global__ __launch_bounds__(256) void gemm_mfma(
    const u16* __restrict__ A0, const u16* __restrict__ A1, const u16* __restrict__ A2,
    const u16* __restrict__ Wa, const u16* __restrict__ Wb, const u16* __restrict__ Wc,
    u16* __restrict__ out, int M){
  __shared__ __align__(16) u16 sA[128 * 40];
  __shared__ __align__(16) u16 sW[128 * 40];
  const int t    = threadIdx.x;
  const int m0   = blockIdx.x * 128;
  const int wid  = t >> 6;
  const int lane = t & 63;
  const int l16  = lane & 15;
  const int kg   = lane >> 4;
  const int nW   = t & 127;      // staging: column owned by this thread
  const int kq   = t >> 7;       // staging: k-half (0..1)

  f32x4 acc[2][8];
  #pragma unroll
  for (int i = 0; i < 2; i++)
    #pragma unroll
    for (int j = 0; j < 8; j++) acc[i][j] = (f32x4){0.f, 0.f, 0.f, 0.f};

  #pragma unroll 1
  for (int s = 0; s < NS; s++){
    const u16* A = (s == 0) ? A0 : (s == 1) ? A1 : A2;
    const u16* W = (s == 0) ? Wa : (s == 1) ? Wb : Wc;
    #pragma unroll 1
    for (int kc = 0; kc < 128; kc += 32){
      // stage A-tile [128 rows][32 k]
      #pragma unroll
      for (int ii = 0; ii < 2; ii++){
        int sl = t + ii * 256;          // 0..511
        int r  = sl >> 2;               // 0..127
        int q  = sl & 3;                // 8-elem group
        int gr = m0 + r;
        uint4 v = make_uint4(0u, 0u, 0u, 0u);
        if (gr < M) v = *(const uint4*)&A[(size_t)gr * 128 + kc + q * 8];
        *(uint4*)&sA[r * 40 + q * 8] = v;
      }
      // stage W chunk transposed: sW[n][k] = W[kc+k][n]; wave-coalesced reads
      {
        __align__(16) u16 wt[16];
        #pragma unroll
        for (int kk = 0; kk < 16; kk++)
          wt[kk] = W[(size_t)(kc + kq * 16 + kk) * 128 + nW];
        *(uint4*)&sW[nW * 40 + kq * 16]     = *(uint4*)&wt[0];
        *(uint4*)&sW[nW * 40 + kq * 16 + 8] = *(uint4*)&wt[8];
      }
      __syncthreads();
      bf16x8 af0 = *(const bf16x8*)&sA[(wid * 32 +      l16) * 40 + kg * 8];
      bf16x8 af1 = *(const bf16x8*)&sA[(wid * 32 + 16 + l16) * 40 + kg * 8];
      #pragma unroll
      for (int ct = 0; ct < 8; ct++){
        bf16x8 bq = *(const bf16x8*)&sW[(ct * 16 + l16) * 40 + kg * 8];
        acc[0][ct] = __builtin_amdgcn_mfma_f32_16x16x32_bf16(af0, bq, acc[0][ct], 0, 0, 0);
        acc[1][ct] = __builtin_amdgcn_mfma_f32_16x16x32_bf16(af1, bq, acc[1][ct], 0, 0, 0);
      }
      __syncthreads();
    }
  }
  // epilogue: D map (HW-verified): col = l16, row = kg*4 + reg (within 16x16 tile)
  #pragma unroll
  for (int rt = 0; rt < 2; rt++){
    #pragma unroll
    for (int reg = 0; reg < 4; reg++){
      int row = m0 + wid * 32 + rt * 16 + kg * 4 + reg;
      if (row < M){
        #pragma unroll
        for (int ct = 0; ct < 8; ct++){
          float v = fmaxf(acc[rt][ct][reg], 0.f);
          out[(size_t)row * 128 + ct * 16 + l16] = (u16)f2bf(v);
        }
      }
    }
  }
}

// ---------------- launch ----------------

extern "C" void kernel_launch(void* const* d_in, const int* in_sizes, int n_in,
                              void* d_out, int out_size, void* d_ws, size_t ws_size,
                              hipStream_t stream){
  const float* x    = (const float*)d_in[0];
  const float* xe   = (const float*)d_in[1];
  const float* gW   = (const float*)d_in[2];
  const float* W0   = (const float*)d_in[3];
  const float* W1   = (const float*)d_in[4];
  const float* W2   = (const float*)d_in[5];
  const float* ldoV = (const float*)d_in[6];
  const float* lupV = (const float*)d_in[7];
  const int*   edges= (const int*)d_in[8];
  const int*   rowi = (const int*)d_in[9];
  const int*   coli = (const int*)d_in[10];
  const int*   ldoI = (const int*)d_in[11];
  const int*   lupI = (const int*)d_in[12];
  (void)n_in; (void)out_size;

  const int D   = 128;
  const int N   = in_sizes[0] / D;
  const int E   = in_sizes[1] / D;
  const int NNZ = in_sizes[6];
  const int L   = in_sizes[2] / (D * D);

  const int* srcN = edges;
  const int* dstN = edges + E;
  const int* ldoR = ldoI;   const int* ldoC = ldoI + NNZ;
  const int* lupR = lupI;   const int* lupC = lupI + NNZ;

  // ---- carve workspace (== R3-proven 237,602,048 B) ----
  size_t off = 0;
  auto carve = [&](size_t bytes) -> void* {
    void* p = (char*)d_ws + off;
    off += (bytes + 255) & ~(size_t)255;
    return p;
  };
  const size_t EBH = (size_t)E * D * 2;             // bf16 E-buffer
  u16* EA  = (u16*)carve(EBH);
  u16* EC  = (u16*)carve(EBH);
  u16* EG1 = (u16*)carve(EBH);
  u16* EG2 = (u16*)carve(EBH);
  float* hA = (float*)carve((size_t)N * D * 4);
  float* hB = (float*)carve((size_t)N * D * 4);
  int* offs_g = (int*)carve((size_t)(N + 1) * 4);
  int* cnt_g  = (int*)carve((size_t)N * 4);
  int* ent_g  = (int*)carve((size_t)E * 4);
  int* offs_d = (int*)carve((size_t)(E + 1) * 4);
  int* cnt_d  = (int*)carve((size_t)E * 4);
  int* entc_d = (int*)carve((size_t)NNZ * 4);
  float* entv_d = (float*)carve((size_t)NNZ * 4);
  int* offs_u = (int*)carve((size_t)(E + 1) * 4);
  int* cnt_u  = (int*)carve((size_t)E * 4);
  int* entc_u = (int*)carve((size_t)NNZ * 4);
  float* entv_u = (float*)carve((size_t)NNZ * 4);
  int* offs_f = (int*)carve((size_t)(N + 1) * 4);
  int* cnt_f  = (int*)carve((size_t)N * 4);
  int* ent_f  = (int*)carve((size_t)2 * E * 4);
  int* partials = (int*)carve(256 * 4);
  if (off > ws_size) return;   // would fail loudly via poisoned output

  // bf16 weights alias hA (GNN finishes with hA before these are written)
  const size_t DD = (size_t)D * D;
  u16* WB0 = (u16*)hA;
  u16* WB1 = WB0 + (size_t)L * DD;
  u16* WB2 = WB1 + (size_t)L * DD;

  auto scan3 = [&](int* cnt, int* offs, int n, int total){
    int nb = (n + SCAN_CHUNK - 1) / SCAN_CHUNK;
    scan_local<<<nb, 256, 0, stream>>>(cnt, offs, partials, n);
    scan_partials_k<<<1, 256, 0, stream>>>(partials, nb);
    scan_add<<<cdiv_h(n, 256), 256, 0, stream>>>(offs, partials, n, total);
  };

  // ---- CSR: GNN (srcs grouped by dst) ----
  hipMemsetAsync(cnt_g, 0, (size_t)N * 4, stream);
  hist_key<<<cdiv_h(E, 256), 256, 0, stream>>>(dstN, cnt_g, E);
  scan3(cnt_g, offs_g, N, E);
  hipMemcpyAsync(cnt_g, offs_g, (size_t)N * 4, hipMemcpyDeviceToDevice, stream);
  fill_plain<<<cdiv_h(E, 256), 256, 0, stream>>>(dstN, srcN, cnt_g, ent_g, E);

  // ---- CSR: Ldo ----
  hipMemsetAsync(cnt_d, 0, (size_t)E * 4, stream);
  hist_key<<<cdiv_h(NNZ, 256), 256, 0, stream>>>(ldoR, cnt_d, NNZ);
  scan3(cnt_d, offs_d, E, NNZ);
  hipMemcpyAsync(cnt_d, offs_d, (size_t)E * 4, hipMemcpyDeviceToDevice, stream);
  fill_wval<<<cdiv_h(NNZ, 256), 256, 0, stream>>>(ldoR, ldoC, ldoV, cnt_d, entc_d, entv_d, NNZ);

  // ---- CSR: Lup ----
  hipMemsetAsync(cnt_u, 0, (size_t)E * 4, stream);
  hist_key<<<cdiv_h(NNZ, 256), 256, 0, stream>>>(lupR, cnt_u, NNZ);
  scan3(cnt_u, offs_u, E, NNZ);
  hipMemcpyAsync(cnt_u, offs_u, (size_t)E * 4, hipMemcpyDeviceToDevice, stream);
  fill_wval<<<cdiv_h(NNZ, 256), 256, 0, stream>>>(lupR, lupC, lupV, cnt_u, entc_u, entv_u, NNZ);

  // ---- CSR: final dual scatter (row + col) ----
  hipMemsetAsync(cnt_f, 0, (size_t)N * 4, stream);
  hist_two<<<cdiv_h(E, 256), 256, 0, stream>>>(rowi, coli, cnt_f, E);
  scan3(cnt_f, offs_f, N, 2 * E);
  hipMemcpyAsync(cnt_f, offs_f, (size_t)N * 4, hipMemcpyDeviceToDevice, stream);
  fill_two<<<cdiv_h(E, 256), 256, 0, stream>>>(rowi, coli, cnt_f, ent_f, E);

  // ---- GNN (fp32): h = relu((h + agg) @ W) x L; last layer -> d_out[:, :128] ----
  const float* hcur = x;
  for (int i = 0; i < L; i++){
    gather_f32<<<cdiv_h(N, 8), 256, 0, stream>>>(hcur, hA, offs_g, ent_g, hcur, N);
    float* hdst = (i == L - 1) ? (float*)d_out : hB;
    int ldo = (i == L - 1) ? 256 : 128;
    gemm_f32<<<cdiv_h(N, 128), 256, 0, stream>>>(hA, gW + (size_t)i * DD, hdst, N, ldo);
    hcur = hB;
  }

  // ---- conversions (after GNN: WB aliases hA) ----
  cvt_f32_bf16<<<cdiv_h(E * D / 8, 256), 256, 0, stream>>>(xe, EA, E * D / 8);
  cvt_f32_bf16<<<cdiv_h((int)(L * DD) / 8, 256), 256, 0, stream>>>(W0, WB0, (int)(L * DD) / 8);
  cvt_f32_bf16<<<cdiv_h((int)(L * DD) / 8, 256), 256, 0, stream>>>(W1, WB1, (int)(L * DD) / 8);
  cvt_f32_bf16<<<cdiv_h((int)(L * DD) / 8, 256), 256, 0, stream>>>(W2, WB2, (int)(L * DD) / 8);

  // ---- CWNN (bf16 MFMA): he = relu(A@W0 + (Ldo@A)@W1 + (Lup@A)@W2) x L ----
  u16* Acur = EA;
  u16* Aalt = EC;
  for (int i = 0; i < L; i++){
    gather_bf16<<<cdiv_h(E, 8), 256, 0, stream>>>(Acur, EG1, offs_d, entc_d, entv_d, E);
    gather_bf16<<<cdiv_h(E, 8), 256, 0, stream>>>(Acur, EG2, offs_u, entc_u, entv_u, E);
    gemm_mfma<3><<<cdiv_h(E, 128), 256, 0, stream>>>(
        Acur, EG1, EG2, WB0 + i * DD, WB1 + i * DD, WB2 + i * DD, Aalt, E);
    u16* tmp = Acur; Acur = Aalt; Aalt = tmp;
  }

  // ---- xed = seg_sum(he, row) + seg_sum(he, col) -> d_out[:, 128:256] ----
  gather_final<<<cdiv_h(N, 8), 256, 0, stream>>>(Acur, (float*)d_out + 128, offs_f, ent_f,
                                                 N, 256);
}

// Round 11
// 798.182 us; speedup vs baseline: 4.0522x; 1.1821x over previous
//
#include <hip/hip_runtime.h>
#include <cstddef>
#include <cstdint>

// CellNetwork on MI355X — round 11 (identical to R7..R10; none ran: infra failures).
// R6 post-mortem: gemm_mfma at 61us had MfmaUtil 12%/VALU 15% — W-staging did 192
// scalar u16 global loads per thread (transpose-on-the-fly). Fix: pre-transpose W
// once (bf16 WT[n][k]), vector staging. Also: CSR build consolidated ~30->9
// dispatches; Ldo/Lup gathers fused+widened to uint4; GNN GEMM retiled BM=64.

using bf16x8 = __attribute__((ext_vector_type(8))) short;
using f32x4  = __attribute__((ext_vector_type(4))) float;
typedef unsigned short u16;
typedef unsigned int   u32;

static inline int cdiv_h(int a, int b){ return (a + b - 1) / b; }

__device__ inline float bflo(u32 u){ return __uint_as_float(u << 16); }
__device__ inline float bfhi(u32 u){ return __uint_as_float(u & 0xFFFF0000u); }
__device__ inline u32 f2bf(float f){
  u32 u = __float_as_uint(f);
  return (u + 0x7FFFu + ((u >> 16) & 1u)) >> 16;
}
__device__ inline u32 pack2(float a, float b){ return f2bf(a) | (f2bf(b) << 16); }
__device__ inline void acc8(float* a, uint4 s, float w){
  a[0] += w * bflo(s.x); a[1] += w * bfhi(s.x);
  a[2] += w * bflo(s.y); a[3] += w * bfhi(s.y);
  a[4] += w * bflo(s.z); a[5] += w * bfhi(s.z);
  a[6] += w * bflo(s.w); a[7] += w * bfhi(s.w);
}

// ---------------- CSR build (consolidated) ----------------
// cnt arrays are carved contiguously: [cnt_d(E) | cnt_u(E) | cnt_g(N) | cnt_f(N)]

__global__ void hist_all(const int* __restrict__ ldoR, const int* __restrict__ lupR,
                         const int* __restrict__ dstN,
                         const int* __restrict__ rowi, const int* __restrict__ coli,
                         int* __restrict__ cnt_d, int* __restrict__ cnt_u,
                         int* __restrict__ cnt_g, int* __restrict__ cnt_f,
                         int nnz, int ne){
  int i = blockIdx.x * blockDim.x + threadIdx.x;
  if (i < nnz){
    atomicAdd(&cnt_d[ldoR[i]], 1);
    atomicAdd(&cnt_u[lupR[i]], 1);
  }
  if (i < ne){
    atomicAdd(&cnt_g[dstN[i]], 1);
    atomicAdd(&cnt_f[rowi[i]], 1);
    atomicAdd(&cnt_f[coli[i]], 1);
  }
}

#define SCAN_CHUNK 2048

// 2-segment batched exclusive scan. cnt segs stride Sc; offs segs stride So.
__global__ void scan_local_multi(const int* __restrict__ cnt, int* __restrict__ offs,
                                 int* __restrict__ partials, int n, int nb,
                                 int Sc, int So){
  int seg = blockIdx.x / nb;
  int lb  = blockIdx.x % nb;
  const int* c = cnt + (size_t)seg * Sc;
  int* o = offs + (size_t)seg * So;
  __shared__ int sd[256];
  int t = threadIdx.x;
  int base = lb * SCAN_CHUNK + t * 8;
  int v[8]; int sum = 0;
  #pragma unroll
  for (int i = 0; i < 8; i++){ int idx = base + i; v[i] = (idx < n) ? c[idx] : 0; sum += v[i]; }
  sd[t] = sum; __syncthreads();
  for (int off = 1; off < 256; off <<= 1){
    int x = (t >= off) ? sd[t - off] : 0;
    __syncthreads();
    sd[t] += x;
    __syncthreads();
  }
  if (t == 255) partials[seg * 256 + lb] = sd[255];
  int run = sd[t] - sum;
  #pragma unroll
  for (int i = 0; i < 8; i++){ int idx = base + i; if (idx < n) o[idx] = run; run += v[i]; }
}

__global__ void scan_partials_multi(int* partials, int nb){
  __shared__ int sd[256];
  int seg = blockIdx.x;
  int t = threadIdx.x;
  int orig = (t < nb) ? partials[seg * 256 + t] : 0;
  sd[t] = orig; __syncthreads();
  for (int off = 1; off < 256; off <<= 1){
    int x = (t >= off) ? sd[t - off] : 0;
    __syncthreads();
    sd[t] += x;
    __syncthreads();
  }
  if (t < nb) partials[seg * 256 + t] = sd[t] - orig;
}

// adds partials, writes cursor (=cnt, repurposed) and offs[n]=total.
__global__ void scan_add_multi(int* __restrict__ offs, int* __restrict__ cnt,
                               const int* __restrict__ partials,
                               int n, int nbAdd, int Sc, int So, int tot0, int tot1){
  int seg = blockIdx.x / nbAdd;
  int il  = (blockIdx.x % nbAdd) * blockDim.x + threadIdx.x;
  int* o = offs + (size_t)seg * So;
  int* c = cnt + (size_t)seg * Sc;
  if (il < n){
    int v = o[il] + partials[seg * 256 + il / SCAN_CHUNK];
    o[il] = v; c[il] = v;
  }
  if (il == 0) o[n] = seg ? tot1 : tot0;
}

__global__ void fill_all(const int* __restrict__ ldoR, const int* __restrict__ ldoC,
                         const float* __restrict__ ldoV,
                         const int* __restrict__ lupR, const int* __restrict__ lupC,
                         const float* __restrict__ lupV,
                         const int* __restrict__ srcN, const int* __restrict__ dstN,
                         const int* __restrict__ rowi, const int* __restrict__ coli,
                         int* __restrict__ cur_d, int* __restrict__ entc_d, float* __restrict__ entv_d,
                         int* __restrict__ cur_u, int* __restrict__ entc_u, float* __restrict__ entv_u,
                         int* __restrict__ cur_g, int* __restrict__ ent_g,
                         int* __restrict__ cur_f, int* __restrict__ ent_f,
                         int nnz, int ne){
  int i = blockIdx.x * blockDim.x + threadIdx.x;
  if (i < nnz){
    int p = atomicAdd(&cur_d[ldoR[i]], 1); entc_d[p] = ldoC[i]; entv_d[p] = ldoV[i];
    int q = atomicAdd(&cur_u[lupR[i]], 1); entc_u[q] = lupC[i]; entv_u[q] = lupV[i];
  }
  if (i < ne){
    int p = atomicAdd(&cur_g[dstN[i]], 1); ent_g[p] = srcN[i];
    int a = atomicAdd(&cur_f[rowi[i]], 1); ent_f[a] = i;
    int b = atomicAdd(&cur_f[coli[i]], 1); ent_f[b] = i;
  }
}

// ---------------- fp32 CSR gather (GNN) ----------------

__global__ void gather_f32(const float* __restrict__ src, float* __restrict__ out,
                           const int* __restrict__ offs, const int* __restrict__ ent,
                           const float* __restrict__ selfsrc, int nrows){
  int r = blockIdx.x * 8 + (threadIdx.x >> 5);
  if (r >= nrows) return;
  int d4 = (threadIdx.x & 31) * 4;
  float4 acc0, acc1 = make_float4(0.f, 0.f, 0.f, 0.f);
  acc0 = *(const float4*)&selfsrc[(size_t)r * 128 + d4];
  int b = offs[r], e = offs[r + 1];
  int j = b;
  for (; j + 1 < e; j += 2){
    int c0 = ent[j], c1 = ent[j + 1];
    float4 s0 = *(const float4*)&src[(size_t)c0 * 128 + d4];
    float4 s1 = *(const float4*)&src[(size_t)c1 * 128 + d4];
    acc0.x += s0.x; acc0.y += s0.y; acc0.z += s0.z; acc0.w += s0.w;
    acc1.x += s1.x; acc1.y += s1.y; acc1.z += s1.z; acc1.w += s1.w;
  }
  if (j < e){
    int c = ent[j];
    float4 s = *(const float4*)&src[(size_t)c * 128 + d4];
    acc0.x += s.x; acc0.y += s.y; acc0.z += s.z; acc0.w += s.w;
  }
  acc0.x += acc1.x; acc0.y += acc1.y; acc0.z += acc1.z; acc0.w += acc1.w;
  *(float4*)&out[(size_t)r * 128 + d4] = acc0;
}

// ---------------- fused bf16 dual gather (Ldo + Lup), uint4-wide ----------------
// grid covers 2*nrows rows: [0,nrows) -> Ldo/out1, [nrows,2*nrows) -> Lup/out2.

__global__ void gather_bf16_dual(const u16* __restrict__ src,
                                 u16* __restrict__ out1, u16* __restrict__ out2,
                                 const int* __restrict__ offs_d, const int* __restrict__ entc_d,
                                 const float* __restrict__ entv_d,
                                 const int* __restrict__ offs_u, const int* __restrict__ entc_u,
                                 const float* __restrict__ entv_u, int nrows){
  int gr = blockIdx.x * 16 + (threadIdx.x >> 4);
  if (gr >= 2 * nrows) return;
  bool up = gr >= nrows;
  int r = up ? gr - nrows : gr;
  const int*   offs = up ? offs_u : offs_d;
  const int*   entc = up ? entc_u : entc_d;
  const float* entv = up ? entv_u : entv_d;
  u16* out = up ? out2 : out1;
  int d8 = (threadIdx.x & 15) * 8;
  float a[8] = {0,0,0,0,0,0,0,0};
  float b[8] = {0,0,0,0,0,0,0,0};
  int be = offs[r], en = offs[r + 1];
  int j = be;
  for (; j + 1 < en; j += 2){
    int c0 = entc[j], c1 = entc[j + 1];
    float w0 = entv[j], w1 = entv[j + 1];
    uint4 s0 = *(const uint4*)&src[(size_t)c0 * 128 + d8];
    uint4 s1 = *(const uint4*)&src[(size_t)c1 * 128 + d8];
    acc8(a, s0, w0);
    acc8(b, s1, w1);
  }
  if (j < en){
    int c = entc[j];
    uint4 s = *(const uint4*)&src[(size_t)c * 128 + d8];
    acc8(a, s, entv[j]);
  }
  uint4 o;
  o.x = pack2(a[0] + b[0], a[1] + b[1]);
  o.y = pack2(a[2] + b[2], a[3] + b[3]);
  o.z = pack2(a[4] + b[4], a[5] + b[5]);
  o.w = pack2(a[6] + b[6], a[7] + b[7]);
  *(uint4*)&out[(size_t)r * 128 + d8] = o;
}

// ---------------- final gather: bf16 src -> fp32 out (ldout=256) ----------------

__global__ void gather_final(const u16* __restrict__ src, float* __restrict__ out,
                             const int* __restrict__ offs, const int* __restrict__ ent,
                             int nrows, int ldout){
  int r = blockIdx.x * 16 + (threadIdx.x >> 4);
  if (r >= nrows) return;
  int d8 = (threadIdx.x & 15) * 8;
  float a[8] = {0,0,0,0,0,0,0,0};
  float b[8] = {0,0,0,0,0,0,0,0};
  int be = offs[r], en = offs[r + 1];
  int j = be;
  for (; j + 1 < en; j += 2){
    int c0 = ent[j], c1 = ent[j + 1];
    uint4 s0 = *(const uint4*)&src[(size_t)c0 * 128 + d8];
    uint4 s1 = *(const uint4*)&src[(size_t)c1 * 128 + d8];
    acc8(a, s0, 1.0f);
    acc8(b, s1, 1.0f);
  }
  if (j < en){
    int c = ent[j];
    uint4 s = *(const uint4*)&src[(size_t)c * 128 + d8];
    acc8(a, s, 1.0f);
  }
  float* op = out + (size_t)r * ldout + d8;
  *(float4*)&op[0] = make_float4(a[0]+b[0], a[1]+b[1], a[2]+b[2], a[3]+b[3]);
  *(float4*)&op[4] = make_float4(a[4]+b[4], a[5]+b[5], a[6]+b[6], a[7]+b[7]);
}

// ---------------- fp32 -> bf16 conversion (xe) ----------------

__global__ void cvt_f32_bf16(const float* __restrict__ src, u16* __restrict__ dst, int n8){
  int i = blockIdx.x * blockDim.x + threadIdx.x;
  if (i >= n8) return;
  const float4* s = (const float4*)(src + (size_t)i * 8);
  float4 a = s[0], c = s[1];
  *(uint4*)(dst + (size_t)i * 8) =
      make_uint4(pack2(a.x, a.y), pack2(a.z, a.w), pack2(c.x, c.y), pack2(c.z, c.w));
}

// ---------------- W transpose+convert: WT[m][n][k] = bf16(W[m][k][n]) ----------------
// thread = (m, g, n): reads 16 k's (coalesced across n), writes 16 contiguous bf16.

__global__ void transp_w(const float* __restrict__ W0, const float* __restrict__ W1,
                         const float* __restrict__ W2, u16* __restrict__ WT, int L){
  int tid = blockIdx.x * blockDim.x + threadIdx.x;
  int total = 3 * L * 8 * 128;
  if (tid >= total) return;
  int n = tid & 127;
  int g = (tid >> 7) & 7;
  int m = tid >> 10;                 // 0 .. 3L-1
  const float* src = (m < L) ? (W0 + (size_t)m * 16384)
                   : (m < 2 * L) ? (W1 + (size_t)(m - L) * 16384)
                   : (W2 + (size_t)(m - 2 * L) * 16384);
  u16* dst = WT + (size_t)m * 16384;
  u16 tmp[16];
  #pragma unroll
  for (int kk = 0; kk < 16; kk++)
    tmp[kk] = (u16)f2bf(src[(size_t)(g * 16 + kk) * 128 + n]);
  *(uint4*)&dst[(size_t)n * 128 + g * 16]     = *(uint4*)&tmp[0];
  *(uint4*)&dst[(size_t)n * 128 + g * 16 + 8] = *(uint4*)&tmp[8];
}

// ---------------- fp32 GEMM (GNN): BM=64, out = relu(in @ W) ----------------

__global__ __launch_bounds__(256) void gemm_f32(
    const float* __restrict__ in, const float* __restrict__ W,
    float* __restrict__ out, int M, int ldout){
  __shared__ float sA[32][68];    // 68*4=272=17*16 -> rows 16B-aligned
  __shared__ float sW[32][128];
  int t  = threadIdx.x;
  int m0 = blockIdx.x * 64;
  int rg = t >> 4;       // 16 groups x 4 rows
  int cg = t & 15;       // 16 groups x 8 cols
  float acc[4][8];
  #pragma unroll
  for (int i = 0; i < 4; i++)
    #pragma unroll
    for (int j = 0; j < 8; j++) acc[i][j] = 0.f;

  for (int kc = 0; kc < 128; kc += 32){
    #pragma unroll
    for (int ii = 0; ii < 2; ii++){
      int s  = t + ii * 256;           // 512 float4 slots: 64 rows x 8 k4
      int r  = s >> 3;
      int k4 = (s & 7) << 2;
      int gr = m0 + r;
      float4 v = (gr < M) ? *(const float4*)&in[(size_t)gr * 128 + kc + k4]
                          : make_float4(0.f, 0.f, 0.f, 0.f);
      sA[k4 + 0][r] = v.x; sA[k4 + 1][r] = v.y; sA[k4 + 2][r] = v.z; sA[k4 + 3][r] = v.w;
    }
    #pragma unroll
    for (int ii = 0; ii < 4; ii++){
      int s  = t + ii * 256;
      int kr = s >> 5;
      int c4 = (s & 31) << 2;
      *(float4*)&sW[kr][c4] = *(const float4*)&W[(size_t)(kc + kr) * 128 + c4];
    }
    __syncthreads();
    #pragma unroll
    for (int k = 0; k < 32; k++){
      float4 a0 = *(const float4*)&sA[k][rg * 4];
      float4 w0 = *(const float4*)&sW[k][cg * 8];
      float4 w1 = *(const float4*)&sW[k][cg * 8 + 4];
      float a[4] = {a0.x, a0.y, a0.z, a0.w};
      float w[8] = {w0.x, w0.y, w0.z, w0.w, w1.x, w1.y, w1.z, w1.w};
      #pragma unroll
      for (int i = 0; i < 4; i++)
        #pragma unroll
        for (int j = 0; j < 8; j++)
          acc[i][j] = fmaf(a[i], w[j], acc[i][j]);
    }
    __syncthreads();
  }
  #pragma unroll
  for (int i = 0; i < 4; i++){
    int gr = m0 + rg * 4 + i;
    if (gr >= M) continue;
    float* op = out + (size_t)gr * ldout + cg * 8;
    #pragma unroll
    for (int jj = 0; jj < 8; jj += 4){
      float4 o = make_float4(fmaxf(acc[i][jj], 0.f), fmaxf(acc[i][jj + 1], 0.f),
                             fmaxf(acc[i][jj + 2], 0.f), fmaxf(acc[i][jj + 3], 0.f));
      *(float4*)&op[jj] = o;
    }
  }
}

// ---------------- bf16 MFMA GEMM (CWNN): out = relu(sum_s As@Ws), bf16 out ------
// W inputs are PRE-TRANSPOSED bf16 (WT[n][k]); staging is all-vector now.

template<int NS>
__global__ __launch_bounds__(256) void gemm_mfma(
    const u16* __restrict__ A0, const u16* __restrict__ A1, const u16* __restrict__ A2,
    const u16* __restrict__ Wa, const u16* __restrict__ Wb, const u16* __restrict__ Wc,
    u16* __restrict__ out, int M){
  __shared__ __align__(16) u16 sA[128 * 40];
  __shared__ __align__(16) u16 sW[128 * 40];
  const int t    = threadIdx.x;
  const int m0   = blockIdx.x * 128;
  const int wid  = t >> 6;
  const int lane = t & 63;
  const int l16  = lane & 15;
  const int kg   = lane >> 4;
  const int nW   = t & 127;
  const int kq   = t >> 7;       // k-half (0..1)

  f32x4 acc[2][8];
  #pragma unroll
  for (int i = 0; i < 2; i++)
    #pragma unroll
    for (int j = 0; j < 8; j++) acc[i][j] = (f32x4){0.f, 0.f, 0.f, 0.f};

  #pragma unroll 1
  for (int s = 0; s < NS; s++){
    const u16* A  = (s == 0) ? A0 : (s == 1) ? A1 : A2;
    const u16* WT = (s == 0) ? Wa : (s == 1) ? Wb : Wc;
    #pragma unroll 1
    for (int kc = 0; kc < 128; kc += 32){
      // stage A-tile [128 rows][32 k] — vector
      #pragma unroll
      for (int ii = 0; ii < 2; ii++){
        int sl = t + ii * 256;
        int r  = sl >> 2;
        int q  = sl & 3;
        int gr = m0 + r;
        uint4 v = make_uint4(0u, 0u, 0u, 0u);
        if (gr < M) v = *(const uint4*)&A[(size_t)gr * 128 + kc + q * 8];
        *(uint4*)&sA[r * 40 + q * 8] = v;
      }
      // stage W chunk from pre-transposed WT — vector (was 16 scalar loads)
      *(uint4*)&sW[nW * 40 + kq * 16]     = *(const uint4*)&WT[(size_t)nW * 128 + kc + kq * 16];
      *(uint4*)&sW[nW * 40 + kq * 16 + 8] = *(const uint4*)&WT[(size_t)nW * 128 + kc + kq * 16 + 8];
      __syncthreads();
      bf16x8 af0 = *(const bf16x8*)&sA[(wid * 32 +      l16) * 40 + kg * 8];
      bf16x8 af1 = *(const bf16x8*)&sA[(wid * 32 + 16 + l16) * 40 + kg * 8];
      #pragma unroll
      for (int ct = 0; ct < 8; ct++){
        bf16x8 bq = *(const bf16x8*)&sW[(ct * 16 + l16) * 40 + kg * 8];
        acc[0][ct] = __builtin_amdgcn_mfma_f32_16x16x32_bf16(af0, bq, acc[0][ct], 0, 0, 0);
        acc[1][ct] = __builtin_amdgcn_mfma_f32_16x16x32_bf16(af1, bq, acc[1][ct], 0, 0, 0);
      }
      __syncthreads();
    }
  }
  // epilogue: D map (HW-verified): col = l16, row = kg*4 + reg
  #pragma unroll
  for (int rt = 0; rt < 2; rt++){
    #pragma unroll
    for (int reg = 0; reg < 4; reg++){
      int row = m0 + wid * 32 + rt * 16 + kg * 4 + reg;
      if (row < M){
        #pragma unroll
        for (int ct = 0; ct < 8; ct++){
          float v = fmaxf(acc[rt][ct][reg], 0.f);
          out[(size_t)row * 128 + ct * 16 + l16] = (u16)f2bf(v);
        }
      }
    }
  }
}

// ---------------- launch ----------------

extern "C" void kernel_launch(void* const* d_in, const int* in_sizes, int n_in,
                              void* d_out, int out_size, void* d_ws, size_t ws_size,
                              hipStream_t stream){
  const float* x    = (const float*)d_in[0];
  const float* xe   = (const float*)d_in[1];
  const float* gW   = (const float*)d_in[2];
  const float* W0   = (const float*)d_in[3];
  const float* W1   = (const float*)d_in[4];
  const float* W2   = (const float*)d_in[5];
  const float* ldoV = (const float*)d_in[6];
  const float* lupV = (const float*)d_in[7];
  const int*   edges= (const int*)d_in[8];
  const int*   rowi = (const int*)d_in[9];
  const int*   coli = (const int*)d_in[10];
  const int*   ldoI = (const int*)d_in[11];
  const int*   lupI = (const int*)d_in[12];
  (void)n_in; (void)out_size;

  const int D   = 128;
  const int N   = in_sizes[0] / D;
  const int E   = in_sizes[1] / D;
  const int NNZ = in_sizes[6];
  const int L   = in_sizes[2] / (D * D);

  const int* srcN = edges;
  const int* dstN = edges + E;
  const int* ldoR = ldoI;   const int* ldoC = ldoI + NNZ;
  const int* lupR = lupI;   const int* lupC = lupI + NNZ;

  // ---- carve workspace (~237.6 MB, same budget as R6-proven) ----
  size_t off = 0;
  auto carve = [&](size_t bytes) -> void* {
    void* p = (char*)d_ws + off;
    off += (bytes + 255) & ~(size_t)255;
    return p;
  };
  const size_t EBH = (size_t)E * D * 2;             // bf16 E-buffer
  u16* EA  = (u16*)carve(EBH);
  u16* EC  = (u16*)carve(EBH);
  u16* EG1 = (u16*)carve(EBH);
  u16* EG2 = (u16*)carve(EBH);
  float* hA = (float*)carve((size_t)N * D * 4);
  float* hB = (float*)carve((size_t)N * D * 4);
  // cnt arrays contiguous: [cnt_d | cnt_u | cnt_g | cnt_f]
  int* cnts   = (int*)carve((size_t)(2 * E + 2 * N) * 4);
  int* cnt_d  = cnts;
  int* cnt_u  = cnts + E;
  int* cnt_g  = cnts + 2 * E;
  int* cnt_f  = cnts + 2 * E + N;
  // offs pairs with uniform stride
  const int SoE = E + 64;
  const int SoN = N + 64;
  int* offsE  = (int*)carve((size_t)2 * SoE * 4);   // [offs_d | offs_u]
  int* offs_d = offsE;
  int* offs_u = offsE + SoE;
  int* offsN  = (int*)carve((size_t)2 * SoN * 4);   // [offs_g | offs_f]
  int* offs_g = offsN;
  int* offs_f = offsN + SoN;
  int* ent_g  = (int*)carve((size_t)E * 4);
  int* entc_d = (int*)carve((size_t)NNZ * 4);
  float* entv_d = (float*)carve((size_t)NNZ * 4);
  int* entc_u = (int*)carve((size_t)NNZ * 4);
  float* entv_u = (float*)carve((size_t)NNZ * 4);
  int* ent_f  = (int*)carve((size_t)2 * E * 4);
  int* partials = (int*)carve(512 * 4);
  if (off > ws_size) return;   // fail loudly via poisoned output

  // transposed bf16 weights alias hA (written only AFTER GNN finishes with hA)
  const size_t DD = (size_t)D * D;
  u16* WTb = (u16*)hA;
  u16* WB0 = WTb;
  u16* WB1 = WTb + (size_t)L * DD;
  u16* WB2 = WTb + (size_t)2 * L * DD;

  // ---- CSR build: 9 dispatches ----
  hipMemsetAsync(cnts, 0, (size_t)(2 * E + 2 * N) * 4, stream);
  hist_all<<<cdiv_h(NNZ, 256), 256, 0, stream>>>(ldoR, lupR, dstN, rowi, coli,
                                                 cnt_d, cnt_u, cnt_g, cnt_f, NNZ, E);
  {
    int nbE = cdiv_h(E, SCAN_CHUNK);
    scan_local_multi<<<2 * nbE, 256, 0, stream>>>(cnt_d, offs_d, partials, E, nbE, E, SoE);
    scan_partials_multi<<<2, 256, 0, stream>>>(partials, nbE);
    int nbAdd = cdiv_h(E, 256);
    scan_add_multi<<<2 * nbAdd, 256, 0, stream>>>(offs_d, cnt_d, partials, E, nbAdd,
                                                  E, SoE, NNZ, NNZ);
  }
  {
    int nbN = cdiv_h(N, SCAN_CHUNK);
    scan_local_multi<<<2 * nbN, 256, 0, stream>>>(cnt_g, offs_g, partials, N, nbN, N, SoN);
    scan_partials_multi<<<2, 256, 0, stream>>>(partials, nbN);
    int nbAdd = cdiv_h(N, 256);
    scan_add_multi<<<2 * nbAdd, 256, 0, stream>>>(offs_g, cnt_g, partials, N, nbAdd,
                                                  N, SoN, E, 2 * E);
  }
  fill_all<<<cdiv_h(NNZ, 256), 256, 0, stream>>>(
      ldoR, ldoC, ldoV, lupR, lupC, lupV, srcN, dstN, rowi, coli,
      cnt_d, entc_d, entv_d, cnt_u, entc_u, entv_u,
      cnt_g, ent_g, cnt_f, ent_f, NNZ, E);

  // ---- GNN (fp32): h = relu((h + agg) @ W) x L; last layer -> d_out[:, :128] ----
  const float* hcur = x;
  for (int i = 0; i < L; i++){
    gather_f32<<<cdiv_h(N, 8), 256, 0, stream>>>(hcur, hA, offs_g, ent_g, hcur, N);
    float* hdst = (i == L - 1) ? (float*)d_out : hB;
    int ldo = (i == L - 1) ? 256 : 128;
    gemm_f32<<<cdiv_h(N, 64), 256, 0, stream>>>(hA, gW + (size_t)i * DD, hdst, N, ldo);
    hcur = hB;
  }

  // ---- conversions (after GNN so WT can alias hA) ----
  cvt_f32_bf16<<<cdiv_h(E * D / 8, 256), 256, 0, stream>>>(xe, EA, E * D / 8);
  transp_w<<<cdiv_h(3 * L * 8 * 128, 256), 256, 0, stream>>>(W0, W1, W2, WTb, L);

  // ---- CWNN (bf16 MFMA): he = relu(A@W0 + (Ldo@A)@W1 + (Lup@A)@W2) x L ----
  u16* Acur = EA;
  u16* Aalt = EC;
  for (int i = 0; i < L; i++){
    gather_bf16_dual<<<cdiv_h(2 * E, 16), 256, 0, stream>>>(
        Acur, EG1, EG2, offs_d, entc_d, entv_d, offs_u, entc_u, entv_u, E);
    gemm_mfma<3><<<cdiv_h(E, 128), 256, 0, stream>>>(
        Acur, EG1, EG2, WB0 + i * DD, WB1 + i * DD, WB2 + i * DD, Aalt, E);
    u16* tmp = Acur; Acur = Aalt; Aalt = tmp;
  }

  // ---- xed = seg_sum(he, row) + seg_sum(he, col) -> d_out[:, 128:256] ----
  gather_final<<<cdiv_h(N, 16), 256, 0, stream>>>(Acur, (float*)d_out + 128, offs_f, ent_f,
                                                  N, 256);
}